// Round 1
// baseline (2154.928 us; speedup 1.0000x reference)
//
#include <hip/hip_runtime.h>

#define T_SEQ 2048
#define BATCH 2
#define HEADS 8
#define DHEAD 64
#define EMB   512

// ---------------------------------------------------------------------------
// Generic fp32 tiled GEMM: C[m,n] = sum_k A[m,k]*Bw[n,k] + bias[n]
// 64x64 block tile, 256 threads, 4x4 per thread, BK=16.
// MODE 0: QKV projection -> scatter into q_s[B,H,T,D], kT[B,H,D,T], v_s[B,H,T,D]
//         (m = t*BATCH + b, n = c in [0,1536))
// MODE 1: pos projection -> rT[n*T + m]  (i.e. r^T, [E, T] = [H*D, T])
// MODE 2: out projection -> out[m*EMB + n]
// All dims here are exact multiples of the tiles (4096/2048 x 1536/512, K=512),
// so no bounds checks.
// ---------------------------------------------------------------------------
template<int MODE>
__global__ __launch_bounds__(256)
void gemm_nt(const float* __restrict__ A, const float* __restrict__ Bw,
             const float* __restrict__ bias, float* __restrict__ out0,
             float* __restrict__ out1, float* __restrict__ out2,
             int M, int N, int K)
{
    __shared__ float As[16][65];
    __shared__ float Bs[16][65];
    const int bm  = blockIdx.y * 64;
    const int bn  = blockIdx.x * 64;
    const int tid = threadIdx.x;
    const int tm  = (tid >> 4) << 2;   // 0..60
    const int tn  = (tid & 15) << 2;   // 0..60

    float acc[4][4] = {};

    for (int k0 = 0; k0 < K; k0 += 16) {
        #pragma unroll
        for (int i = tid; i < 64 * 16; i += 256) {
            const int mm = i >> 4, kk = i & 15;
            As[kk][mm] = A [(size_t)(bm + mm) * K + k0 + kk];
            Bs[kk][mm] = Bw[(size_t)(bn + mm) * K + k0 + kk];
        }
        __syncthreads();
        #pragma unroll
        for (int kk = 0; kk < 16; ++kk) {
            const float a0 = As[kk][tm + 0], a1 = As[kk][tm + 1];
            const float a2 = As[kk][tm + 2], a3 = As[kk][tm + 3];
            const float b0 = Bs[kk][tn + 0], b1 = Bs[kk][tn + 1];
            const float b2 = Bs[kk][tn + 2], b3 = Bs[kk][tn + 3];
            acc[0][0] += a0 * b0; acc[0][1] += a0 * b1; acc[0][2] += a0 * b2; acc[0][3] += a0 * b3;
            acc[1][0] += a1 * b0; acc[1][1] += a1 * b1; acc[1][2] += a1 * b2; acc[1][3] += a1 * b3;
            acc[2][0] += a2 * b0; acc[2][1] += a2 * b1; acc[2][2] += a2 * b2; acc[2][3] += a2 * b3;
            acc[3][0] += a3 * b0; acc[3][1] += a3 * b1; acc[3][2] += a3 * b2; acc[3][3] += a3 * b3;
        }
        __syncthreads();
    }

    #pragma unroll
    for (int i = 0; i < 4; ++i) {
        const int m = bm + tm + i;
        #pragma unroll
        for (int j = 0; j < 4; ++j) {
            const int n = bn + tn + j;
            const float val = acc[i][j] + bias[n];
            if (MODE == 0) {
                const int t = m >> 1, b = m & 1;   // m = t*BATCH + b, BATCH=2
                if (n < EMB) {
                    const int h = n >> 6, dd = n & 63;
                    out0[((size_t)(b * HEADS + h) * T_SEQ + t) * DHEAD + dd] = val;
                } else if (n < 2 * EMB) {
                    const int c = n - EMB, h = c >> 6, dd = c & 63;
                    out1[((size_t)(b * HEADS + h) * DHEAD + dd) * T_SEQ + t] = val;
                } else {
                    const int c = n - 2 * EMB, h = c >> 6, dd = c & 63;
                    out2[((size_t)(b * HEADS + h) * T_SEQ + t) * DHEAD + dd] = val;
                }
            } else if (MODE == 1) {
                out0[(size_t)n * T_SEQ + m] = val;   // rT[c][j]
            } else {
                out0[(size_t)m * EMB + n] = val;     // final output [T,B,E]
            }
        }
    }
}

// ---------------------------------------------------------------------------
// Attention: one block per (b,h,t) query row. Scores for all 2048 keys in LDS,
// two-pass softmax, then P·V with 4-way partial reduction.
//
// rel_shift semantics (exact, incl. the reference's wrap-around garbage):
//   bd_shift[t,s] = (q[t]  +rr)·r[T-1-t+s]  for s <= t
//                 = 0                        for s == t+1
//                 = (q[t+1]+rr)·r[s-t-2]     for s >  t+1
// ---------------------------------------------------------------------------
__global__ __launch_bounds__(256)
void attn_kernel(const float* __restrict__ q_s, const float* __restrict__ kT,
                 const float* __restrict__ v_s, const float* __restrict__ rT,
                 const float* __restrict__ rwb, const float* __restrict__ rrb,
                 float* __restrict__ ctx)
{
    const int T   = T_SEQ;
    const int t   = blockIdx.x;
    const int bh  = blockIdx.y;       // b*HEADS + h
    const int h   = bh & 7;
    const int b   = bh >> 3;
    const int tid = threadIdx.x;
    const int lane = tid & 63, wave = tid >> 6;

    __shared__ float sc[T_SEQ];              // 8 KB
    __shared__ float qrw[64], qrr[64], qrr2[64];
    __shared__ float red[8];
    __shared__ float cred[256];

    if (tid < 64) {
        const float qv = q_s[((size_t)bh * T + t) * DHEAD + tid];
        const float rr = rrb[h * 64 + tid];
        qrw[tid]  = qv + rwb[h * 64 + tid];
        qrr[tid]  = qv + rr;
        const float q2 = (t + 1 < T) ? q_s[((size_t)bh * T + t + 1) * DHEAD + tid] : 0.f;
        qrr2[tid] = q2 + rr;
    }
    __syncthreads();

    const float* kb = kT + (size_t)bh * DHEAD * T;   // [d][s]
    const float* rb = rT + (size_t)h  * DHEAD * T;   // [d][j]

    // ---- scores ----
    for (int s = tid; s < T; s += 256) {
        const bool  lower = (s <= t);
        const float* qv = lower ? qrr : qrr2;
        int j = lower ? (T - 1 - t + s) : (s - t - 2);
        if (j < 0) j = 0;                    // s == t+1 -> dummy, zeroed below
        float ac = 0.f, bd = 0.f;
        #pragma unroll 16
        for (int d = 0; d < 64; ++d) {
            ac += qrw[d] * kb[(size_t)d * T + s];
            bd += qv[d]  * rb[(size_t)d * T + j];
        }
        if (s == t + 1) bd = 0.f;
        sc[s] = (ac + bd) * 0.125f;          // scale = 1/sqrt(64)
    }
    __syncthreads();

    // ---- softmax: max ----
    float m = -3.4e38f;
    for (int s = tid; s < T; s += 256) m = fmaxf(m, sc[s]);
    #pragma unroll
    for (int off = 32; off; off >>= 1) m = fmaxf(m, __shfl_down(m, off));
    if (lane == 0) red[wave] = m;
    __syncthreads();
    m = fmaxf(fmaxf(red[0], red[1]), fmaxf(red[2], red[3]));

    // ---- softmax: exp + sum (sc left unnormalized; fold 1/l at the end) ----
    float lsum = 0.f;
    for (int s = tid; s < T; s += 256) {
        const float e = __expf(sc[s] - m);
        sc[s] = e;
        lsum += e;
    }
    #pragma unroll
    for (int off = 32; off; off >>= 1) lsum += __shfl_down(lsum, off);
    if (lane == 0) red[4 + wave] = lsum;
    __syncthreads();
    const float inv = 1.f / (red[4] + red[5] + red[6] + red[7]);

    // ---- ctx = P · V ----
    const int dd = tid & 63, g = tid >> 6;
    const float* vb = v_s + (size_t)bh * T * DHEAD + dd;
    float acc = 0.f;
    for (int s = g * 512; s < (g + 1) * 512; ++s)
        acc += sc[s] * vb[(size_t)s * DHEAD];
    cred[tid] = acc * inv;
    __syncthreads();
    if (tid < 64) {
        const float r = cred[tid] + cred[64 + tid] + cred[128 + tid] + cred[192 + tid];
        ctx[((size_t)t * BATCH + b) * EMB + h * 64 + tid] = r;
    }
}

// ---------------------------------------------------------------------------
// Workspace layout (floats):
//   q_s  [B,H,T,D]  @ 0         (2,097,152)
//   kT   [B,H,D,T]  @ 2097152   (2,097,152)
//   v_s  [B,H,T,D]  @ 4194304   (2,097,152)
//   rT   [H,D,T]    @ 6291456   (1,048,576)
//   ctx  [T,B,E]    @ 7340032   (2,097,152)
// total 9,437,184 floats = 37.75 MB
// ---------------------------------------------------------------------------
extern "C" void kernel_launch(void* const* d_in, const int* in_sizes, int n_in,
                              void* d_out, int out_size, void* d_ws, size_t ws_size,
                              hipStream_t stream)
{
    const float* input = (const float*)d_in[0];
    const float* pos   = (const float*)d_in[1];
    const float* w_in  = (const float*)d_in[2];
    const float* w_out = (const float*)d_in[3];
    const float* w_pos = (const float*)d_in[4];
    const float* b_in  = (const float*)d_in[5];
    const float* b_out = (const float*)d_in[6];
    const float* b_pos = (const float*)d_in[7];
    const float* rwb   = (const float*)d_in[8];
    const float* rrb   = (const float*)d_in[9];

    float* ws  = (float*)d_ws;
    float* q_s = ws;
    float* kT  = ws + 2097152;
    float* v_s = ws + 4194304;
    float* rT  = ws + 6291456;
    float* ctx = ws + 7340032;
    float* out = (float*)d_out;

    // QKV projection: M=4096 (t*B+b), N=1536, K=512
    gemm_nt<0><<<dim3(24, 64), 256, 0, stream>>>(input, w_in, b_in, q_s, kT, v_s,
                                                 T_SEQ * BATCH, 3 * EMB, EMB);
    // pos projection: M=2048, N=512, K=512 -> rT
    gemm_nt<1><<<dim3(8, 32), 256, 0, stream>>>(pos, w_pos, b_pos, rT, nullptr, nullptr,
                                                T_SEQ, EMB, EMB);
    // attention
    attn_kernel<<<dim3(T_SEQ, BATCH * HEADS), 256, 0, stream>>>(q_s, kT, v_s, rT,
                                                                rwb, rrb, ctx);
    // out projection: M=4096, N=512, K=512
    gemm_nt<2><<<dim3(8, 64), 256, 0, stream>>>(ctx, w_out, b_out, out, nullptr, nullptr,
                                                T_SEQ * BATCH, EMB, EMB);
}

// Round 2
// 617.715 us; speedup vs baseline: 3.4885x; 3.4885x over previous
//
#include <hip/hip_runtime.h>

#define T_SEQ 2048
#define BATCH 2
#define HEADS 8
#define DHEAD 64
#define EMB   512

typedef __attribute__((ext_vector_type(8))) short short8;
typedef __attribute__((ext_vector_type(4))) short short4v;
typedef __attribute__((ext_vector_type(4))) float floatx4;

__device__ __forceinline__ unsigned short f2b(float f) {
    union { float f; unsigned u; } v; v.f = f;
    unsigned r = v.u + 0x7fffu + ((v.u >> 16) & 1u);   // RNE to bf16
    return (unsigned short)(r >> 16);
}
__device__ __forceinline__ float b2f(unsigned short s) {
    union { unsigned u; float f; } v; v.u = ((unsigned)s) << 16; return v.f;
}
// 8 consecutive bf16 from LDS (8B-aligned) as an MFMA operand
__device__ __forceinline__ short8 ld_frag(const unsigned short* p) {
    short4v lo = *(const short4v*)p;
    short4v hi = *(const short4v*)(p + 4);
    short8 r;
    r[0] = lo[0]; r[1] = lo[1]; r[2] = lo[2]; r[3] = lo[3];
    r[4] = hi[0]; r[5] = hi[1]; r[6] = hi[2]; r[7] = hi[3];
    return r;
}
#define MFMA16(a, b, c) __builtin_amdgcn_mfma_f32_16x16x32_bf16(a, b, c, 0, 0, 0)

// ---------------------------------------------------------------------------
// fp32 projection GEMM: C[m,n] = sum_k A[m,k]*Bw[n,k] + bias[n]
// MODE 0: QKV -> q_s[B,H,T,D], k_s[B,H,T,D], vT[B,H,D,T]
// MODE 1: pos -> r natural [R, E]
// MODE 2: out -> out[m*EMB + n]
// ---------------------------------------------------------------------------
template<int MODE>
__global__ __launch_bounds__(256)
void gemm_nt(const float* __restrict__ A, const float* __restrict__ Bw,
             const float* __restrict__ bias, float* __restrict__ out0,
             float* __restrict__ out1, float* __restrict__ out2,
             int M, int N, int K)
{
    __shared__ float As[16][65];
    __shared__ float Bs[16][65];
    const int bm  = blockIdx.y * 64;
    const int bn  = blockIdx.x * 64;
    const int tid = threadIdx.x;
    const int tm  = (tid >> 4) << 2;
    const int tn  = (tid & 15) << 2;

    float acc[4][4] = {};

    for (int k0 = 0; k0 < K; k0 += 16) {
        #pragma unroll
        for (int i = tid; i < 64 * 16; i += 256) {
            const int mm = i >> 4, kk = i & 15;
            As[kk][mm] = A [(size_t)(bm + mm) * K + k0 + kk];
            Bs[kk][mm] = Bw[(size_t)(bn + mm) * K + k0 + kk];
        }
        __syncthreads();
        #pragma unroll
        for (int kk = 0; kk < 16; ++kk) {
            const float a0 = As[kk][tm + 0], a1 = As[kk][tm + 1];
            const float a2 = As[kk][tm + 2], a3 = As[kk][tm + 3];
            const float b0 = Bs[kk][tn + 0], b1 = Bs[kk][tn + 1];
            const float b2 = Bs[kk][tn + 2], b3 = Bs[kk][tn + 3];
            acc[0][0] += a0 * b0; acc[0][1] += a0 * b1; acc[0][2] += a0 * b2; acc[0][3] += a0 * b3;
            acc[1][0] += a1 * b0; acc[1][1] += a1 * b1; acc[1][2] += a1 * b2; acc[1][3] += a1 * b3;
            acc[2][0] += a2 * b0; acc[2][1] += a2 * b1; acc[2][2] += a2 * b2; acc[2][3] += a2 * b3;
            acc[3][0] += a3 * b0; acc[3][1] += a3 * b1; acc[3][2] += a3 * b2; acc[3][3] += a3 * b3;
        }
        __syncthreads();
    }

    #pragma unroll
    for (int i = 0; i < 4; ++i) {
        const int m = bm + tm + i;
        #pragma unroll
        for (int j = 0; j < 4; ++j) {
            const int n = bn + tn + j;
            const float val = acc[i][j] + bias[n];
            if (MODE == 0) {
                const int t = m >> 1, b = m & 1;
                if (n < EMB) {
                    const int h = n >> 6, dd = n & 63;
                    out0[((size_t)(b * HEADS + h) * T_SEQ + t) * DHEAD + dd] = val;
                } else if (n < 2 * EMB) {
                    const int c = n - EMB, h = c >> 6, dd = c & 63;
                    out1[((size_t)(b * HEADS + h) * T_SEQ + t) * DHEAD + dd] = val;
                } else {
                    const int c = n - 2 * EMB, h = c >> 6, dd = c & 63;
                    out2[((size_t)(b * HEADS + h) * DHEAD + dd) * T_SEQ + t] = val;
                }
            } else if (MODE == 1) {
                out0[(size_t)m * EMB + n] = val;
            } else {
                out0[(size_t)m * EMB + n] = val;
            }
        }
    }
}

// ---------------------------------------------------------------------------
// Fused MFMA attention. Block = 64 query rows (4 waves x 16) for one (b,h).
// S-tiles of 64. rel_shift:
//   bd[t][s] = QR[t][T-1-t+s]   (s <= t)   "lower",  window jw = s0+T-t0-64
//            = 0                (s == t+1)
//            = QR[t+1][s-t-2]   (s >= t+2) "upper",  window jw = s0-t0-65
// Both cases read QP[i][63-i+u] with i = block row, u = s-s0; upper uses
// A-rows shifted by +1 (qrr staged with 65 rows).
// Only the s0==t0 tile needs both passes.
// ---------------------------------------------------------------------------
__global__ __launch_bounds__(256)
void attn_mfma(const float* __restrict__ qg_, const float* __restrict__ kg_,
               const float* __restrict__ vtg_, const float* __restrict__ rg_,
               const float* __restrict__ rwb, const float* __restrict__ rrb,
               float* __restrict__ ctx)
{
    const int T   = T_SEQ;
    const int t0  = blockIdx.x * 64;
    const int bh  = blockIdx.y;
    const int h   = bh & 7;
    const int b   = bh >> 3;
    const int tid = threadIdx.x;
    const int lane = tid & 63;
    const int w    = tid >> 6;
    const int m16  = lane & 15;
    const int quad = lane >> 4;

    __shared__ unsigned short qrw_s[64 * 72];   // (q+rw)/8, rows t0..t0+63
    __shared__ unsigned short qrr_s[65 * 72];   // (q+rr)/8, rows t0..t0+64
    __shared__ unsigned short kv_s [64 * 72];   // K tile [s][d]  /  Vt tile [d][s]
    __shared__ unsigned short r_s  [128 * 72];  // r window [j][d]
    __shared__ unsigned short qp_s [64 * 128];  // QR tile (stride 128) / P tile (stride 72)

    const float* qg  = qg_  + ((size_t)bh * T + t0) * DHEAD;
    const float* kg  = kg_  + (size_t)bh * T * DHEAD;
    const float* vtg = vtg_ + (size_t)bh * DHEAD * T;
    const float* rg  = rg_  + h * DHEAD;

    // ---- stage q tiles (pre-scaled by 1/8, biases added) ----
    for (int idx = tid; idx < 65 * 16; idx += 256) {
        const int row = idx >> 4, c = (idx & 15) << 2;
        float4 qv;
        if (t0 + row < T) qv = *(const float4*)(qg + row * DHEAD + c);
        else { qv.x = 0.f; qv.y = 0.f; qv.z = 0.f; qv.w = 0.f; }
        const float4 rr = *(const float4*)(rrb + h * DHEAD + c);
        qrr_s[row * 72 + c + 0] = f2b((qv.x + rr.x) * 0.125f);
        qrr_s[row * 72 + c + 1] = f2b((qv.y + rr.y) * 0.125f);
        qrr_s[row * 72 + c + 2] = f2b((qv.z + rr.z) * 0.125f);
        qrr_s[row * 72 + c + 3] = f2b((qv.w + rr.w) * 0.125f);
        if (row < 64) {
            const float4 rw = *(const float4*)(rwb + h * DHEAD + c);
            qrw_s[row * 72 + c + 0] = f2b((qv.x + rw.x) * 0.125f);
            qrw_s[row * 72 + c + 1] = f2b((qv.y + rw.y) * 0.125f);
            qrw_s[row * 72 + c + 2] = f2b((qv.z + rw.z) * 0.125f);
            qrw_s[row * 72 + c + 3] = f2b((qv.w + rw.w) * 0.125f);
        }
    }
    __syncthreads();

    // loop-invariant A-fragments
    short8 a_ac[2], a_qrl[2], a_qru[2];
    {
        const unsigned short* p0 = &qrw_s[(16 * w + m16) * 72 + quad * 8];
        a_ac[0]  = ld_frag(p0);  a_ac[1]  = ld_frag(p0 + 32);
        const unsigned short* p1 = &qrr_s[(16 * w + m16) * 72 + quad * 8];
        a_qrl[0] = ld_frag(p1);  a_qrl[1] = ld_frag(p1 + 32);
        const unsigned short* p2 = &qrr_s[(16 * w + 1 + m16) * 72 + quad * 8];
        a_qru[0] = ld_frag(p2);  a_qru[1] = ld_frag(p2 + 32);
    }

    floatx4 O[4];
    float mrun[4], lrun[4];
    #pragma unroll
    for (int ct = 0; ct < 4; ++ct) O[ct] = (floatx4){0.f, 0.f, 0.f, 0.f};
    #pragma unroll
    for (int rgi = 0; rgi < 4; ++rgi) { mrun[rgi] = -3.4e38f; lrun[rgi] = 0.f; }

    for (int s0 = 0; s0 < T; s0 += 64) {
        const bool low1 = (s0 <= t0);

        // ---- stage K tile + r window ----
        for (int idx = tid; idx < 64 * 16; idx += 256) {
            const int row = idx >> 4, c = (idx & 15) << 2;
            const float4 kvv = *(const float4*)(kg + (size_t)(s0 + row) * DHEAD + c);
            kv_s[row * 72 + c + 0] = f2b(kvv.x);
            kv_s[row * 72 + c + 1] = f2b(kvv.y);
            kv_s[row * 72 + c + 2] = f2b(kvv.z);
            kv_s[row * 72 + c + 3] = f2b(kvv.w);
        }
        const int jw1 = low1 ? (s0 + T - t0 - 64) : (s0 - t0 - 65);
        for (int idx = tid; idx < 128 * 16; idx += 256) {
            const int row = idx >> 4, c = (idx & 15) << 2;
            int j = jw1 + row; j = j < 0 ? 0 : (j > T - 1 ? T - 1 : j);
            const float4 rv = *(const float4*)(rg + (size_t)j * EMB + c);
            r_s[row * 72 + c + 0] = f2b(rv.x);
            r_s[row * 72 + c + 1] = f2b(rv.y);
            r_s[row * 72 + c + 2] = f2b(rv.z);
            r_s[row * 72 + c + 3] = f2b(rv.w);
        }
        __syncthreads();                                   // B0

        // ---- AC ----
        floatx4 acf[4];
        #pragma unroll
        for (int ct = 0; ct < 4; ++ct) {
            acf[ct] = (floatx4){0.f, 0.f, 0.f, 0.f};
            #pragma unroll
            for (int ks = 0; ks < 2; ++ks) {
                short8 bfr = ld_frag(&kv_s[(16 * ct + m16) * 72 + ks * 32 + quad * 8]);
                acf[ct] = MFMA16(a_ac[ks], bfr, acf[ct]);
            }
        }
        // ---- QR pass 1 ----
        #pragma unroll
        for (int cc = 0; cc < 8; ++cc) {
            floatx4 q4 = (floatx4){0.f, 0.f, 0.f, 0.f};
            #pragma unroll
            for (int ks = 0; ks < 2; ++ks) {
                short8 bfr = ld_frag(&r_s[(16 * cc + m16) * 72 + ks * 32 + quad * 8]);
                q4 = MFMA16(low1 ? a_qrl[ks] : a_qru[ks], bfr, q4);
            }
            #pragma unroll
            for (int rgi = 0; rgi < 4; ++rgi)
                qp_s[(16 * w + quad * 4 + rgi) * 128 + 16 * cc + m16] = f2b(q4[rgi]);
        }
        __syncthreads();                                   // B1

        // ---- assemble pass 1 ----
        #pragma unroll
        for (int ct = 0; ct < 4; ++ct) {
            #pragma unroll
            for (int rgi = 0; rgi < 4; ++rgi) {
                const int i = 16 * w + quad * 4 + rgi;
                const int t = t0 + i;
                const int u = 16 * ct + m16;
                const int s = s0 + u;
                const bool take = low1 ? (s <= t) : (s >= t + 2);
                if (take) acf[ct][rgi] += b2f(qp_s[i * 128 + 63 - i + u]);
            }
        }

        // ---- transition tile: second (upper) pass ----
        if (s0 == t0) {
            __syncthreads();                               // Bt1
            const int jw2 = s0 - t0 - 65;
            for (int idx = tid; idx < 128 * 16; idx += 256) {
                const int row = idx >> 4, c = (idx & 15) << 2;
                int j = jw2 + row; j = j < 0 ? 0 : (j > T - 1 ? T - 1 : j);
                const float4 rv = *(const float4*)(rg + (size_t)j * EMB + c);
                r_s[row * 72 + c + 0] = f2b(rv.x);
                r_s[row * 72 + c + 1] = f2b(rv.y);
                r_s[row * 72 + c + 2] = f2b(rv.z);
                r_s[row * 72 + c + 3] = f2b(rv.w);
            }
            __syncthreads();                               // Bt2
            #pragma unroll
            for (int cc = 0; cc < 8; ++cc) {
                floatx4 q4 = (floatx4){0.f, 0.f, 0.f, 0.f};
                #pragma unroll
                for (int ks = 0; ks < 2; ++ks) {
                    short8 bfr = ld_frag(&r_s[(16 * cc + m16) * 72 + ks * 32 + quad * 8]);
                    q4 = MFMA16(a_qru[ks], bfr, q4);
                }
                #pragma unroll
                for (int rgi = 0; rgi < 4; ++rgi)
                    qp_s[(16 * w + quad * 4 + rgi) * 128 + 16 * cc + m16] = f2b(q4[rgi]);
            }
            __syncthreads();                               // Bt3
            #pragma unroll
            for (int ct = 0; ct < 4; ++ct) {
                #pragma unroll
                for (int rgi = 0; rgi < 4; ++rgi) {
                    const int i = 16 * w + quad * 4 + rgi;
                    const int t = t0 + i;
                    const int u = 16 * ct + m16;
                    const int s = s0 + u;
                    if (s >= t + 2) acf[ct][rgi] += b2f(qp_s[i * 128 + 63 - i + u]);
                }
            }
        }

        // ---- online softmax (scores pre-scaled via q) ----
        float alpha[4];
        #pragma unroll
        for (int rgi = 0; rgi < 4; ++rgi) {
            float mx = fmaxf(fmaxf(acf[0][rgi], acf[1][rgi]),
                             fmaxf(acf[2][rgi], acf[3][rgi]));
            #pragma unroll
            for (int off = 1; off < 16; off <<= 1)
                mx = fmaxf(mx, __shfl_xor(mx, off));
            const float mn = fmaxf(mrun[rgi], mx);
            alpha[rgi] = __expf(mrun[rgi] - mn);
            mrun[rgi] = mn;
            float s4 = 0.f;
            #pragma unroll
            for (int ct = 0; ct < 4; ++ct) {
                const float p = __expf(acf[ct][rgi] - mn);
                acf[ct][rgi] = p;
                s4 += p;
            }
            #pragma unroll
            for (int off = 1; off < 16; off <<= 1)
                s4 += __shfl_xor(s4, off);
            lrun[rgi] = lrun[rgi] * alpha[rgi] + s4;
        }
        #pragma unroll
        for (int ct = 0; ct < 4; ++ct)
            #pragma unroll
            for (int rgi = 0; rgi < 4; ++rgi) O[ct][rgi] *= alpha[rgi];

        __syncthreads();                                   // B2

        // ---- write P (stride 72) + stage Vt ----
        #pragma unroll
        for (int ct = 0; ct < 4; ++ct)
            #pragma unroll
            for (int rgi = 0; rgi < 4; ++rgi)
                qp_s[(16 * w + quad * 4 + rgi) * 72 + 16 * ct + m16] = f2b(acf[ct][rgi]);
        for (int idx = tid; idx < 64 * 16; idx += 256) {
            const int row = idx >> 4, c = (idx & 15) << 2;
            const float4 vv = *(const float4*)(vtg + (size_t)row * T + s0 + c);
            kv_s[row * 72 + c + 0] = f2b(vv.x);
            kv_s[row * 72 + c + 1] = f2b(vv.y);
            kv_s[row * 72 + c + 2] = f2b(vv.z);
            kv_s[row * 72 + c + 3] = f2b(vv.w);
        }
        __syncthreads();                                   // B3

        // ---- PV ----
        short8 ap[2];
        {
            const unsigned short* p = &qp_s[(16 * w + m16) * 72 + quad * 8];
            ap[0] = ld_frag(p); ap[1] = ld_frag(p + 32);
        }
        #pragma unroll
        for (int ct = 0; ct < 4; ++ct) {
            #pragma unroll
            for (int ks = 0; ks < 2; ++ks) {
                short8 bfr = ld_frag(&kv_s[(16 * ct + m16) * 72 + ks * 32 + quad * 8]);
                O[ct] = MFMA16(ap[ks], bfr, O[ct]);
            }
        }
        __syncthreads();                                   // B4
    }

    // ---- write ctx [T,B,E] ----
    #pragma unroll
    for (int rgi = 0; rgi < 4; ++rgi) {
        const int t = t0 + 16 * w + quad * 4 + rgi;
        const float inv = 1.f / lrun[rgi];
        #pragma unroll
        for (int ct = 0; ct < 4; ++ct)
            ctx[((size_t)t * BATCH + b) * EMB + h * DHEAD + 16 * ct + m16] = O[ct][rgi] * inv;
    }
}

// ---------------------------------------------------------------------------
// Workspace (floats): q_s 2097152 | k_s 2097152 | vT 2097152 | r 1048576 |
// ctx 2097152  -> 9,437,184 floats = 37.75 MB
// ---------------------------------------------------------------------------
extern "C" void kernel_launch(void* const* d_in, const int* in_sizes, int n_in,
                              void* d_out, int out_size, void* d_ws, size_t ws_size,
                              hipStream_t stream)
{
    const float* input = (const float*)d_in[0];
    const float* pos   = (const float*)d_in[1];
    const float* w_in  = (const float*)d_in[2];
    const float* w_out = (const float*)d_in[3];
    const float* w_pos = (const float*)d_in[4];
    const float* b_in  = (const float*)d_in[5];
    const float* b_out = (const float*)d_in[6];
    const float* b_pos = (const float*)d_in[7];
    const float* rwb   = (const float*)d_in[8];
    const float* rrb   = (const float*)d_in[9];

    float* ws  = (float*)d_ws;
    float* q_s = ws;
    float* k_s = ws + 2097152;
    float* vT  = ws + 4194304;
    float* r_n = ws + 6291456;
    float* ctx = ws + 7340032;
    float* out = (float*)d_out;

    gemm_nt<0><<<dim3(24, 64), 256, 0, stream>>>(input, w_in, b_in, q_s, k_s, vT,
                                                 T_SEQ * BATCH, 3 * EMB, EMB);
    gemm_nt<1><<<dim3(8, 32), 256, 0, stream>>>(pos, w_pos, b_pos, r_n, nullptr, nullptr,
                                                T_SEQ, EMB, EMB);
    attn_mfma<<<dim3(T_SEQ / 64, BATCH * HEADS), 256, 0, stream>>>(q_s, k_s, vT, r_n,
                                                                   rwb, rrb, ctx);
    gemm_nt<2><<<dim3(8, 64), 256, 0, stream>>>(ctx, w_out, b_out, out, nullptr, nullptr,
                                                T_SEQ * BATCH, EMB, EMB);
}

// Round 3
// 319.177 us; speedup vs baseline: 6.7515x; 1.9353x over previous
//
#include <hip/hip_runtime.h>

#define T_SEQ 2048
#define BATCH 2
#define HEADS 8
#define DHEAD 64
#define EMB   512

typedef __attribute__((ext_vector_type(8))) short short8;
typedef __attribute__((ext_vector_type(4))) short short4v;
typedef __attribute__((ext_vector_type(4))) float floatx4;
typedef __attribute__((ext_vector_type(8))) unsigned short ushort8;
typedef __attribute__((ext_vector_type(4))) unsigned short ushort4v;

__device__ __forceinline__ unsigned short f2b(float f) {
    union { float f; unsigned u; } v; v.f = f;
    unsigned r = v.u + 0x7fffu + ((v.u >> 16) & 1u);   // RNE to bf16
    return (unsigned short)(r >> 16);
}
__device__ __forceinline__ float b2f(unsigned short s) {
    union { unsigned u; float f; } v; v.u = ((unsigned)s) << 16; return v.f;
}
__device__ __forceinline__ short8 ld_frag(const unsigned short* p) {
    short4v lo = *(const short4v*)p;
    short4v hi = *(const short4v*)(p + 4);
    short8 r;
    r[0] = lo[0]; r[1] = lo[1]; r[2] = lo[2]; r[3] = lo[3];
    r[4] = hi[0]; r[5] = hi[1]; r[6] = hi[2]; r[7] = hi[3];
    return r;
}
__device__ __forceinline__ void st8(unsigned short* p, ushort8 v) {
    ushort4v lo = { v[0], v[1], v[2], v[3] };
    ushort4v hi = { v[4], v[5], v[6], v[7] };
    *(ushort4v*)p = lo;
    *(ushort4v*)(p + 4) = hi;
}
#define MFMA16(a, b, c) __builtin_amdgcn_mfma_f32_16x16x32_bf16(a, b, c, 0, 0, 0)

// ---------------------------------------------------------------------------
// fp32 -> bf16 bulk convert (n4 = count/4)
// ---------------------------------------------------------------------------
__global__ __launch_bounds__(256)
void cvt_bf16(const float* __restrict__ in, unsigned short* __restrict__ out, int n4)
{
    const int i = blockIdx.x * 256 + threadIdx.x;
    if (i < n4) {
        const float4 v = ((const float4*)in)[i];
        ushort4v o = { f2b(v.x), f2b(v.y), f2b(v.z), f2b(v.w) };
        ((ushort4v*)out)[i] = o;
    }
}

// ---------------------------------------------------------------------------
// bf16 MFMA GEMM: C[m,n] = sum_k A[m,k]*B[n,k] + bias[n]
// 128x128 tile, 4 waves in 2x2, each wave 64x64 (4x4 frags of 16x16x32), BK=32.
// MODE 0: QKV -> q_s/k_s/v_s bf16 [B,H,T,D]
// MODE 1: pos -> r bf16 [R,E]
// MODE 2: out -> fp32 [m*EMB+n]
// ---------------------------------------------------------------------------
template<int MODE>
__global__ __launch_bounds__(256)
void gemm_bf16(const unsigned short* __restrict__ A, const unsigned short* __restrict__ B,
               const float* __restrict__ bias, void* __restrict__ out0,
               void* __restrict__ out1, void* __restrict__ out2, int K)
{
    __shared__ unsigned short As[128 * 36];
    __shared__ unsigned short Bs[128 * 36];
    const int bm  = blockIdx.y * 128;
    const int bn  = blockIdx.x * 128;
    const int tid = threadIdx.x;
    const int lane = tid & 63, w = tid >> 6;
    const int m16 = lane & 15, quad = lane >> 4;
    const int wm = (w & 1) * 64, wn = (w >> 1) * 64;

    floatx4 acc[4][4];
    #pragma unroll
    for (int i = 0; i < 4; ++i)
        #pragma unroll
        for (int j = 0; j < 4; ++j) acc[i][j] = (floatx4){0.f, 0.f, 0.f, 0.f};

    for (int k0 = 0; k0 < K; k0 += 32) {
        #pragma unroll
        for (int s = tid; s < 512; s += 256) {
            const int row = s >> 2, c = (s & 3) * 8;
            st8(&As[row * 36 + c], *(const ushort8*)(A + (size_t)(bm + row) * K + k0 + c));
            st8(&Bs[row * 36 + c], *(const ushort8*)(B + (size_t)(bn + row) * K + k0 + c));
        }
        __syncthreads();
        short8 af[4], bf[4];
        #pragma unroll
        for (int f = 0; f < 4; ++f) {
            af[f] = ld_frag(&As[(wm + f * 16 + m16) * 36 + quad * 8]);
            bf[f] = ld_frag(&Bs[(wn + f * 16 + m16) * 36 + quad * 8]);
        }
        #pragma unroll
        for (int fm = 0; fm < 4; ++fm)
            #pragma unroll
            for (int fn = 0; fn < 4; ++fn)
                acc[fm][fn] = MFMA16(af[fm], bf[fn], acc[fm][fn]);
        __syncthreads();
    }

    #pragma unroll
    for (int fn = 0; fn < 4; ++fn) {
        const int n = bn + wn + fn * 16 + m16;
        const float bv = bias[n];
        #pragma unroll
        for (int fm = 0; fm < 4; ++fm) {
            #pragma unroll
            for (int rgi = 0; rgi < 4; ++rgi) {
                const int m = bm + wm + fm * 16 + quad * 4 + rgi;
                const float val = acc[fm][fn][rgi] + bv;
                if (MODE == 0) {
                    const int t = m >> 1, b = m & 1;
                    const int reg = n >> 9, c = n & 511, h = c >> 6, dd = c & 63;
                    unsigned short* dst = (unsigned short*)(reg == 0 ? out0 : (reg == 1 ? out1 : out2));
                    dst[((size_t)(b * HEADS + h) * T_SEQ + t) * DHEAD + dd] = f2b(val);
                } else if (MODE == 1) {
                    ((unsigned short*)out0)[(size_t)m * EMB + n] = f2b(val);
                } else {
                    ((float*)out0)[(size_t)m * EMB + n] = val;
                }
            }
        }
    }
}

// ---------------------------------------------------------------------------
// bf16 transpose: v_s [B,H,T,D] -> vT [B,H,D,T]; 64x64 tiles.
// ---------------------------------------------------------------------------
__global__ __launch_bounds__(256)
void transpose_v(const unsigned short* __restrict__ v_s, unsigned short* __restrict__ vT)
{
    __shared__ unsigned short tile[64 * 68];
    const int t0 = blockIdx.x * 64, bh = blockIdx.y;
    const int tid = threadIdx.x;
    const unsigned short* src = v_s + ((size_t)bh * T_SEQ + t0) * DHEAD;
    #pragma unroll
    for (int s = tid; s < 512; s += 256) {
        const int row = s >> 3, c = (s & 7) * 8;
        st8(&tile[row * 68 + c], *(const ushort8*)(src + row * DHEAD + c));
    }
    __syncthreads();
    unsigned short* dst = vT + (size_t)bh * DHEAD * T_SEQ + t0;
    #pragma unroll
    for (int s = tid; s < 512; s += 256) {
        const int d = s >> 3, c = (s & 7) * 8;
        ushort8 o;
        #pragma unroll
        for (int j = 0; j < 8; ++j) o[j] = tile[(c + j) * 68 + d];
        *(ushort8*)(dst + (size_t)d * T_SEQ + c) = o;
    }
}

// ---------------------------------------------------------------------------
// Fused MFMA attention (all-bf16 inputs). Block = 64 query rows for one (b,h).
//   bd[t][s] = QR[t][T-1-t+s]  (s<=t) | 0 (s==t+1) | QR[t+1][s-t-2] (s>=t+2)
// ---------------------------------------------------------------------------
__global__ __launch_bounds__(256)
void attn_mfma(const unsigned short* __restrict__ qg_, const unsigned short* __restrict__ kg_,
               const unsigned short* __restrict__ vtg_, const unsigned short* __restrict__ rg_,
               const float* __restrict__ rwb, const float* __restrict__ rrb,
               unsigned short* __restrict__ ctx)
{
    const int T   = T_SEQ;
    const int t0  = blockIdx.x * 64;
    const int bh  = blockIdx.y;
    const int h   = bh & 7;
    const int b   = bh >> 3;
    const int tid = threadIdx.x;
    const int lane = tid & 63;
    const int w    = tid >> 6;
    const int m16  = lane & 15;
    const int quad = lane >> 4;

    __shared__ unsigned short qrw_s[64 * 68];
    __shared__ unsigned short qrr_s[65 * 68];
    __shared__ unsigned short kv_s [64 * 68];
    __shared__ unsigned short r_s  [128 * 68];
    __shared__ unsigned short qp_s [64 * 130];   // QR (stride 130) / P (stride 68)

    const unsigned short* qg  = qg_  + ((size_t)bh * T + t0) * DHEAD;
    const unsigned short* kg  = kg_  + (size_t)bh * T * DHEAD;
    const unsigned short* vtg = vtg_ + (size_t)bh * DHEAD * T;
    const unsigned short* rg  = rg_  + h * DHEAD;

    // ---- stage q tiles: (q + bias) * 0.125, bf16 ----
    for (int idx = tid; idx < 65 * 16; idx += 256) {
        const int row = idx >> 4, c = (idx & 15) << 2;
        ushort4v qv = {0, 0, 0, 0};
        if (t0 + row < T) qv = *(const ushort4v*)(qg + row * DHEAD + c);
        const float4 rr = *(const float4*)(rrb + h * DHEAD + c);
        qrr_s[row * 68 + c + 0] = f2b((b2f(qv[0]) + rr.x) * 0.125f);
        qrr_s[row * 68 + c + 1] = f2b((b2f(qv[1]) + rr.y) * 0.125f);
        qrr_s[row * 68 + c + 2] = f2b((b2f(qv[2]) + rr.z) * 0.125f);
        qrr_s[row * 68 + c + 3] = f2b((b2f(qv[3]) + rr.w) * 0.125f);
        if (row < 64) {
            const float4 rw = *(const float4*)(rwb + h * DHEAD + c);
            qrw_s[row * 68 + c + 0] = f2b((b2f(qv[0]) + rw.x) * 0.125f);
            qrw_s[row * 68 + c + 1] = f2b((b2f(qv[1]) + rw.y) * 0.125f);
            qrw_s[row * 68 + c + 2] = f2b((b2f(qv[2]) + rw.z) * 0.125f);
            qrw_s[row * 68 + c + 3] = f2b((b2f(qv[3]) + rw.w) * 0.125f);
        }
    }
    __syncthreads();

    short8 a_ac[2], a_qrl[2], a_qru[2];
    {
        const unsigned short* p0 = &qrw_s[(16 * w + m16) * 68 + quad * 8];
        a_ac[0]  = ld_frag(p0);  a_ac[1]  = ld_frag(p0 + 32);
        const unsigned short* p1 = &qrr_s[(16 * w + m16) * 68 + quad * 8];
        a_qrl[0] = ld_frag(p1);  a_qrl[1] = ld_frag(p1 + 32);
        const unsigned short* p2 = &qrr_s[(16 * w + 1 + m16) * 68 + quad * 8];
        a_qru[0] = ld_frag(p2);  a_qru[1] = ld_frag(p2 + 32);
    }

    floatx4 O[4];
    float mrun[4], lrun[4];
    #pragma unroll
    for (int ct = 0; ct < 4; ++ct) O[ct] = (floatx4){0.f, 0.f, 0.f, 0.f};
    #pragma unroll
    for (int rgi = 0; rgi < 4; ++rgi) { mrun[rgi] = -3.4e38f; lrun[rgi] = 0.f; }

    for (int s0 = 0; s0 < T; s0 += 64) {
        const bool low1 = (s0 <= t0);

        // ---- stage K tile + r window (pure bf16 copies) ----
        #pragma unroll
        for (int idx = tid; idx < 512; idx += 256) {
            const int row = idx >> 3, c = (idx & 7) * 8;
            st8(&kv_s[row * 68 + c], *(const ushort8*)(kg + (size_t)(s0 + row) * DHEAD + c));
        }
        const int jw1 = low1 ? (s0 + T - t0 - 64) : (s0 - t0 - 65);
        for (int idx = tid; idx < 1024; idx += 256) {
            const int row = idx >> 3, c = (idx & 7) * 8;
            int j = jw1 + row; j = j < 0 ? 0 : (j > T - 1 ? T - 1 : j);
            st8(&r_s[row * 68 + c], *(const ushort8*)(rg + (size_t)j * EMB + c));
        }
        __syncthreads();                                   // B0

        // ---- AC ----
        floatx4 acf[4];
        #pragma unroll
        for (int ct = 0; ct < 4; ++ct) {
            acf[ct] = (floatx4){0.f, 0.f, 0.f, 0.f};
            #pragma unroll
            for (int ks = 0; ks < 2; ++ks) {
                short8 bfr = ld_frag(&kv_s[(16 * ct + m16) * 68 + ks * 32 + quad * 8]);
                acf[ct] = MFMA16(a_ac[ks], bfr, acf[ct]);
            }
        }
        // ---- QR pass 1 ----
        #pragma unroll
        for (int cc = 0; cc < 8; ++cc) {
            floatx4 q4 = (floatx4){0.f, 0.f, 0.f, 0.f};
            #pragma unroll
            for (int ks = 0; ks < 2; ++ks) {
                short8 bfr = ld_frag(&r_s[(16 * cc + m16) * 68 + ks * 32 + quad * 8]);
                q4 = MFMA16(low1 ? a_qrl[ks] : a_qru[ks], bfr, q4);
            }
            #pragma unroll
            for (int rgi = 0; rgi < 4; ++rgi)
                qp_s[(16 * w + quad * 4 + rgi) * 130 + 16 * cc + m16] = f2b(q4[rgi]);
        }
        __syncthreads();                                   // B1

        // ---- assemble pass 1 ----
        #pragma unroll
        for (int ct = 0; ct < 4; ++ct) {
            #pragma unroll
            for (int rgi = 0; rgi < 4; ++rgi) {
                const int i = 16 * w + quad * 4 + rgi;
                const int t = t0 + i;
                const int u = 16 * ct + m16;
                const int s = s0 + u;
                const bool take = low1 ? (s <= t) : (s >= t + 2);
                if (take) acf[ct][rgi] += b2f(qp_s[i * 130 + 63 - i + u]);
            }
        }

        // ---- transition tile: second (upper) pass ----
        if (s0 == t0) {
            __syncthreads();                               // Bt1
            const int jw2 = s0 - t0 - 65;
            for (int idx = tid; idx < 1024; idx += 256) {
                const int row = idx >> 3, c = (idx & 7) * 8;
                int j = jw2 + row; j = j < 0 ? 0 : (j > T - 1 ? T - 1 : j);
                st8(&r_s[row * 68 + c], *(const ushort8*)(rg + (size_t)j * EMB + c));
            }
            __syncthreads();                               // Bt2
            #pragma unroll
            for (int cc = 0; cc < 8; ++cc) {
                floatx4 q4 = (floatx4){0.f, 0.f, 0.f, 0.f};
                #pragma unroll
                for (int ks = 0; ks < 2; ++ks) {
                    short8 bfr = ld_frag(&r_s[(16 * cc + m16) * 68 + ks * 32 + quad * 8]);
                    q4 = MFMA16(a_qru[ks], bfr, q4);
                }
                #pragma unroll
                for (int rgi = 0; rgi < 4; ++rgi)
                    qp_s[(16 * w + quad * 4 + rgi) * 130 + 16 * cc + m16] = f2b(q4[rgi]);
            }
            __syncthreads();                               // Bt3
            #pragma unroll
            for (int ct = 0; ct < 4; ++ct) {
                #pragma unroll
                for (int rgi = 0; rgi < 4; ++rgi) {
                    const int i = 16 * w + quad * 4 + rgi;
                    const int t = t0 + i;
                    const int u = 16 * ct + m16;
                    const int s = s0 + u;
                    if (s >= t + 2) acf[ct][rgi] += b2f(qp_s[i * 130 + 63 - i + u]);
                }
            }
        }

        // ---- online softmax ----
        float alpha[4];
        #pragma unroll
        for (int rgi = 0; rgi < 4; ++rgi) {
            float mx = fmaxf(fmaxf(acf[0][rgi], acf[1][rgi]),
                             fmaxf(acf[2][rgi], acf[3][rgi]));
            #pragma unroll
            for (int off = 1; off < 16; off <<= 1)
                mx = fmaxf(mx, __shfl_xor(mx, off));
            const float mn = fmaxf(mrun[rgi], mx);
            alpha[rgi] = __expf(mrun[rgi] - mn);
            mrun[rgi] = mn;
            float s4 = 0.f;
            #pragma unroll
            for (int ct = 0; ct < 4; ++ct) {
                const float p = __expf(acf[ct][rgi] - mn);
                acf[ct][rgi] = p;
                s4 += p;
            }
            #pragma unroll
            for (int off = 1; off < 16; off <<= 1)
                s4 += __shfl_xor(s4, off);
            lrun[rgi] = lrun[rgi] * alpha[rgi] + s4;
        }
        #pragma unroll
        for (int ct = 0; ct < 4; ++ct)
            #pragma unroll
            for (int rgi = 0; rgi < 4; ++rgi) O[ct][rgi] *= alpha[rgi];

        __syncthreads();                                   // B2

        // ---- write P (stride 68) + stage Vt ----
        #pragma unroll
        for (int ct = 0; ct < 4; ++ct)
            #pragma unroll
            for (int rgi = 0; rgi < 4; ++rgi)
                qp_s[(16 * w + quad * 4 + rgi) * 68 + 16 * ct + m16] = f2b(acf[ct][rgi]);
        #pragma unroll
        for (int idx = tid; idx < 512; idx += 256) {
            const int row = idx >> 3, c = (idx & 7) * 8;
            st8(&kv_s[row * 68 + c], *(const ushort8*)(vtg + (size_t)row * T + s0 + c));
        }
        __syncthreads();                                   // B3

        // ---- PV ----
        short8 ap[2];
        {
            const unsigned short* p = &qp_s[(16 * w + m16) * 68 + quad * 8];
            ap[0] = ld_frag(p); ap[1] = ld_frag(p + 32);
        }
        #pragma unroll
        for (int ct = 0; ct < 4; ++ct) {
            #pragma unroll
            for (int ks = 0; ks < 2; ++ks) {
                short8 bfr = ld_frag(&kv_s[(16 * ct + m16) * 68 + ks * 32 + quad * 8]);
                O[ct] = MFMA16(ap[ks], bfr, O[ct]);
            }
        }
        __syncthreads();                                   // B4
    }

    // ---- write ctx bf16 [T,B,E] ----
    #pragma unroll
    for (int rgi = 0; rgi < 4; ++rgi) {
        const int t = t0 + 16 * w + quad * 4 + rgi;
        const float inv = 1.f / lrun[rgi];
        #pragma unroll
        for (int ct = 0; ct < 4; ++ct)
            ctx[((size_t)t * BATCH + b) * EMB + h * DHEAD + 16 * ct + m16] = f2b(O[ct][rgi] * inv);
    }
}

// ---------------------------------------------------------------------------
// Workspace (ushort offsets):
//  inb 0 | posb 2097152 | w_inb 3145728 | w_posb 3932160 | w_outb 4194304 |
//  q_s 4456448 | k_s 6553600 | v_s 8650752 | vT 10747904 | r_b 12845056 |
//  ctx_b 13893632 | end 15990784 (= 30.5 MB)
// ---------------------------------------------------------------------------
extern "C" void kernel_launch(void* const* d_in, const int* in_sizes, int n_in,
                              void* d_out, int out_size, void* d_ws, size_t ws_size,
                              hipStream_t stream)
{
    const float* input = (const float*)d_in[0];
    const float* pos   = (const float*)d_in[1];
    const float* w_in  = (const float*)d_in[2];
    const float* w_out = (const float*)d_in[3];
    const float* w_pos = (const float*)d_in[4];
    const float* b_in  = (const float*)d_in[5];
    const float* b_out = (const float*)d_in[6];
    const float* b_pos = (const float*)d_in[7];
    const float* rwb   = (const float*)d_in[8];
    const float* rrb   = (const float*)d_in[9];

    unsigned short* ws    = (unsigned short*)d_ws;
    unsigned short* inb   = ws;
    unsigned short* posb  = ws + 2097152;
    unsigned short* w_inb = ws + 3145728;
    unsigned short* w_posb= ws + 3932160;
    unsigned short* w_outb= ws + 4194304;
    unsigned short* q_s   = ws + 4456448;
    unsigned short* k_s   = ws + 6553600;
    unsigned short* v_s   = ws + 8650752;
    unsigned short* vT    = ws + 10747904;
    unsigned short* r_b   = ws + 12845056;
    unsigned short* ctx_b = ws + 13893632;

    cvt_bf16<<<2048, 256, 0, stream>>>(input, inb,    524288);
    cvt_bf16<<<1024, 256, 0, stream>>>(pos,   posb,   262144);
    cvt_bf16<<< 768, 256, 0, stream>>>(w_in,  w_inb,  196608);
    cvt_bf16<<< 256, 256, 0, stream>>>(w_pos, w_posb,  65536);
    cvt_bf16<<< 256, 256, 0, stream>>>(w_out, w_outb,  65536);

    gemm_bf16<0><<<dim3(12, 32), 256, 0, stream>>>(inb, w_inb, b_in, q_s, k_s, v_s, EMB);
    gemm_bf16<1><<<dim3(4, 16), 256, 0, stream>>>(posb, w_posb, b_pos, r_b, nullptr, nullptr, EMB);
    transpose_v<<<dim3(32, 16), 256, 0, stream>>>(v_s, vT);
    attn_mfma<<<dim3(32, 16), 256, 0, stream>>>(q_s, k_s, vT, r_b, rwb, rrb, ctx_b);
    gemm_bf16<2><<<dim3(4, 32), 256, 0, stream>>>(ctx_b, w_outb, b_out, d_out, nullptr, nullptr, EMB);
}

// Round 4
// 291.939 us; speedup vs baseline: 7.3814x; 1.0933x over previous
//
#include <hip/hip_runtime.h>

#define T_SEQ 2048
#define BATCH 2
#define HEADS 8
#define DHEAD 64
#define EMB   512

typedef __attribute__((ext_vector_type(8))) short short8;
typedef __attribute__((ext_vector_type(4))) short short4v;
typedef __attribute__((ext_vector_type(4))) float floatx4;
typedef __attribute__((ext_vector_type(8))) unsigned short ushort8;
typedef __attribute__((ext_vector_type(4))) unsigned short ushort4v;

__device__ __forceinline__ unsigned short f2b(float f) {
    union { float f; unsigned u; } v; v.f = f;
    unsigned r = v.u + 0x7fffu + ((v.u >> 16) & 1u);   // RNE to bf16
    return (unsigned short)(r >> 16);
}
__device__ __forceinline__ float b2f(unsigned short s) {
    union { unsigned u; float f; } v; v.u = ((unsigned)s) << 16; return v.f;
}
__device__ __forceinline__ short8 ld_frag(const unsigned short* p) {
    short4v lo = *(const short4v*)p;
    short4v hi = *(const short4v*)(p + 4);
    short8 r;
    r[0] = lo[0]; r[1] = lo[1]; r[2] = lo[2]; r[3] = lo[3];
    r[4] = hi[0]; r[5] = hi[1]; r[6] = hi[2]; r[7] = hi[3];
    return r;
}
__device__ __forceinline__ void st8(unsigned short* p, ushort8 v) {
    ushort4v lo = { v[0], v[1], v[2], v[3] };
    ushort4v hi = { v[4], v[5], v[6], v[7] };
    *(ushort4v*)p = lo;
    *(ushort4v*)(p + 4) = hi;
}
#define MFMA16(a, b, c) __builtin_amdgcn_mfma_f32_16x16x32_bf16(a, b, c, 0, 0, 0)

// ---------------------------------------------------------------------------
// bf16 MFMA GEMM, fp32 inputs converted during LDS staging.
// C[m,n] = sum_k A[m,k]*B[n,k] + bias[n]; 128x128 tile, 4 waves 2x2, BK=32.
// MODE 0: A fp32 input, B fp32 w_in   -> q_s/k_s/v_s bf16 [B,H,T,D]
// MODE 1: A fp32 pos,   B fp32 w_pos  -> r bf16 [R,E]
// MODE 2: A bf16 ctx,   B fp32 w_out  -> fp32 out [m*EMB+n]
// ---------------------------------------------------------------------------
template<int MODE>
__global__ __launch_bounds__(256)
void gemm_bf16(const void* __restrict__ A_, const float* __restrict__ Bw,
               const float* __restrict__ bias, void* __restrict__ out0,
               void* __restrict__ out1, void* __restrict__ out2, int K)
{
    __shared__ unsigned short As[128 * 36];
    __shared__ unsigned short Bs[128 * 36];
    const int bm  = blockIdx.y * 128;
    const int bn  = blockIdx.x * 128;
    const int tid = threadIdx.x;
    const int lane = tid & 63, w = tid >> 6;
    const int m16 = lane & 15, quad = lane >> 4;
    const int wm = (w & 1) * 64, wn = (w >> 1) * 64;

    floatx4 acc[4][4];
    #pragma unroll
    for (int i = 0; i < 4; ++i)
        #pragma unroll
        for (int j = 0; j < 4; ++j) acc[i][j] = (floatx4){0.f, 0.f, 0.f, 0.f};

    for (int k0 = 0; k0 < K; k0 += 32) {
        #pragma unroll
        for (int s = tid; s < 512; s += 256) {
            const int row = s >> 2, c = (s & 3) * 8;
            if (MODE == 2) {
                st8(&As[row * 36 + c],
                    *(const ushort8*)((const unsigned short*)A_ + (size_t)(bm + row) * K + k0 + c));
            } else {
                const float* pa = (const float*)A_ + (size_t)(bm + row) * K + k0 + c;
                const float4 x = *(const float4*)pa, y = *(const float4*)(pa + 4);
                ushort8 o = { f2b(x.x), f2b(x.y), f2b(x.z), f2b(x.w),
                              f2b(y.x), f2b(y.y), f2b(y.z), f2b(y.w) };
                st8(&As[row * 36 + c], o);
            }
            const float* pb = Bw + (size_t)(bn + row) * K + k0 + c;
            const float4 bx = *(const float4*)pb, by = *(const float4*)(pb + 4);
            ushort8 ob = { f2b(bx.x), f2b(bx.y), f2b(bx.z), f2b(bx.w),
                           f2b(by.x), f2b(by.y), f2b(by.z), f2b(by.w) };
            st8(&Bs[row * 36 + c], ob);
        }
        __syncthreads();
        short8 af[4], bf[4];
        #pragma unroll
        for (int f = 0; f < 4; ++f) {
            af[f] = ld_frag(&As[(wm + f * 16 + m16) * 36 + quad * 8]);
            bf[f] = ld_frag(&Bs[(wn + f * 16 + m16) * 36 + quad * 8]);
        }
        #pragma unroll
        for (int fm = 0; fm < 4; ++fm)
            #pragma unroll
            for (int fn = 0; fn < 4; ++fn)
                acc[fm][fn] = MFMA16(af[fm], bf[fn], acc[fm][fn]);
        __syncthreads();
    }

    #pragma unroll
    for (int fn = 0; fn < 4; ++fn) {
        const int n = bn + wn + fn * 16 + m16;
        const float bv = bias[n];
        #pragma unroll
        for (int fm = 0; fm < 4; ++fm) {
            #pragma unroll
            for (int rgi = 0; rgi < 4; ++rgi) {
                const int m = bm + wm + fm * 16 + quad * 4 + rgi;
                const float val = acc[fm][fn][rgi] + bv;
                if (MODE == 0) {
                    const int t = m >> 1, b = m & 1;
                    const int reg = n >> 9, c = n & 511, h = c >> 6, dd = c & 63;
                    unsigned short* dst = (unsigned short*)(reg == 0 ? out0 : (reg == 1 ? out1 : out2));
                    dst[((size_t)(b * HEADS + h) * T_SEQ + t) * DHEAD + dd] = f2b(val);
                } else if (MODE == 1) {
                    ((unsigned short*)out0)[(size_t)m * EMB + n] = f2b(val);
                } else {
                    ((float*)out0)[(size_t)m * EMB + n] = val;
                }
            }
        }
    }
}

// ---------------------------------------------------------------------------
// bf16 transpose: v_s [B,H,T,D] -> vT [B,H,D,T]
// ---------------------------------------------------------------------------
__global__ __launch_bounds__(256)
void transpose_v(const unsigned short* __restrict__ v_s, unsigned short* __restrict__ vT)
{
    __shared__ unsigned short tile[64 * 68];
    const int t0 = blockIdx.x * 64, bh = blockIdx.y;
    const int tid = threadIdx.x;
    const unsigned short* src = v_s + ((size_t)bh * T_SEQ + t0) * DHEAD;
    #pragma unroll
    for (int s = tid; s < 512; s += 256) {
        const int row = s >> 3, c = (s & 7) * 8;
        st8(&tile[row * 68 + c], *(const ushort8*)(src + row * DHEAD + c));
    }
    __syncthreads();
    unsigned short* dst = vT + (size_t)bh * DHEAD * T_SEQ + t0;
    #pragma unroll
    for (int s = tid; s < 512; s += 256) {
        const int d = s >> 3, c = (s & 7) * 8;
        ushort8 o;
        #pragma unroll
        for (int j = 0; j < 8; ++j) o[j] = tile[(c + j) * 68 + d];
        *(ushort8*)(dst + (size_t)d * T_SEQ + c) = o;
    }
}

// ---------------------------------------------------------------------------
// Fused MFMA attention with rolling-QR ring.
//   bd[t][s] = QR[t][T-1-t+s]  (s<=t) | 0 (s==t+1) | QR[t+1][s-t-2] (s>=t+2)
// Per s-tile the 128-wide QR window slides by 64: only the new 64 columns are
// computed (8 MFMAs); results live in a 128-column LDS ring (qp).
// Phases: lower (s0<=t0, A=q+rr rows t0..), upper (s0>=t0, A=rows t0+1..).
// Phase start pays a full-window prologue; transition tile (s0==t0) runs the
// lower path then the upper prologue + upper assemble.
// LDS (ushort offs): [qrw 0 | qrr 4352] UNION [r_s 0 | k_ls 4352] ; v_ls 8776 ;
// p_s 13128 ; qp 17480 (stride 133). Total 51984 B -> 3 blocks/CU.
// ---------------------------------------------------------------------------
__global__ __launch_bounds__(256)
void attn_mfma(const unsigned short* __restrict__ qg_, const unsigned short* __restrict__ kg_,
               const unsigned short* __restrict__ vtg_, const unsigned short* __restrict__ rg_,
               const float* __restrict__ rwb, const float* __restrict__ rrb,
               unsigned short* __restrict__ ctx)
{
    const int T   = T_SEQ;
    const int t0  = blockIdx.x * 64;
    const int bh  = blockIdx.y;
    const int h   = bh & 7;
    const int b   = bh >> 3;
    const int tid = threadIdx.x;
    const int lane = tid & 63;
    const int w    = tid >> 6;
    const int m16  = lane & 15;
    const int quad = lane >> 4;

    __shared__ unsigned short lds[25992];
    unsigned short* qrw_s = lds;            // 64 x 68 (pre-loop)
    unsigned short* qrr_s = lds + 4352;     // 65 x 68 (pre-loop)
    unsigned short* r_s   = lds;            // 64 x 68 (in-loop, aliases qrw)
    unsigned short* k_ls  = lds + 4352;     // 64 x 68 (in-loop, aliases qrr)
    unsigned short* v_ls  = lds + 8776;     // 64 x 68
    unsigned short* p_s   = lds + 13128;    // 64 x 68
    unsigned short* qp_s  = lds + 17480;    // 64 x 133 ring (cols 0..127 used)

    const unsigned short* qg  = qg_  + ((size_t)bh * T + t0) * DHEAD;
    const unsigned short* kg  = kg_  + (size_t)bh * T * DHEAD;
    const unsigned short* vtg = vtg_ + (size_t)bh * DHEAD * T;
    const unsigned short* rg  = rg_  + h * DHEAD;

    // ---- stage q tiles: (q + bias) * 0.125, bf16 ----
    for (int idx = tid; idx < 65 * 16; idx += 256) {
        const int row = idx >> 4, c = (idx & 15) << 2;
        ushort4v qv = {0, 0, 0, 0};
        if (t0 + row < T) qv = *(const ushort4v*)(qg + row * DHEAD + c);
        const float4 rr = *(const float4*)(rrb + h * DHEAD + c);
        qrr_s[row * 68 + c + 0] = f2b((b2f(qv[0]) + rr.x) * 0.125f);
        qrr_s[row * 68 + c + 1] = f2b((b2f(qv[1]) + rr.y) * 0.125f);
        qrr_s[row * 68 + c + 2] = f2b((b2f(qv[2]) + rr.z) * 0.125f);
        qrr_s[row * 68 + c + 3] = f2b((b2f(qv[3]) + rr.w) * 0.125f);
        if (row < 64) {
            const float4 rw = *(const float4*)(rwb + h * DHEAD + c);
            qrw_s[row * 68 + c + 0] = f2b((b2f(qv[0]) + rw.x) * 0.125f);
            qrw_s[row * 68 + c + 1] = f2b((b2f(qv[1]) + rw.y) * 0.125f);
            qrw_s[row * 68 + c + 2] = f2b((b2f(qv[2]) + rw.z) * 0.125f);
            qrw_s[row * 68 + c + 3] = f2b((b2f(qv[3]) + rw.w) * 0.125f);
        }
    }
    __syncthreads();

    short8 a_ac[2], a_qrl[2], a_qru[2];
    {
        const unsigned short* p0 = &qrw_s[(16 * w + m16) * 68 + quad * 8];
        a_ac[0]  = ld_frag(p0);  a_ac[1]  = ld_frag(p0 + 32);
        const unsigned short* p1 = &qrr_s[(16 * w + m16) * 68 + quad * 8];
        a_qrl[0] = ld_frag(p1);  a_qrl[1] = ld_frag(p1 + 32);
        const unsigned short* p2 = &qrr_s[(16 * w + 1 + m16) * 68 + quad * 8];
        a_qru[0] = ld_frag(p2);  a_qru[1] = ld_frag(p2 + 32);
    }
    __syncthreads();   // region A reads done; safe to reuse as r_s/k_ls

    // staging / QR helpers
    auto stage_r = [&](int jbase) {
        for (int idx = tid; idx < 512; idx += 256) {
            const int row = idx >> 3, c = (idx & 7) * 8;
            int j = jbase + row; j = j < 0 ? 0 : (j > T - 1 ? T - 1 : j);
            st8(&r_s[row * 68 + c], *(const ushort8*)(rg + (size_t)j * EMB + c));
        }
    };
    auto qr_half = [&](const short8* aq, int slotbase) {
        #pragma unroll
        for (int cc = 0; cc < 4; ++cc) {
            floatx4 q4 = (floatx4){0.f, 0.f, 0.f, 0.f};
            #pragma unroll
            for (int ks = 0; ks < 2; ++ks) {
                short8 bfr = ld_frag(&r_s[(16 * cc + m16) * 68 + ks * 32 + quad * 8]);
                q4 = MFMA16(aq[ks], bfr, q4);
            }
            #pragma unroll
            for (int rgi = 0; rgi < 4; ++rgi)
                qp_s[(16 * w + quad * 4 + rgi) * 133 + slotbase + 16 * cc + m16] = f2b(q4[rgi]);
        }
    };

    floatx4 O[4];
    float mrun[4], lrun[4];
    #pragma unroll
    for (int ct = 0; ct < 4; ++ct) O[ct] = (floatx4){0.f, 0.f, 0.f, 0.f};
    #pragma unroll
    for (int rgi = 0; rgi < 4; ++rgi) { mrun[rgi] = -3.4e38f; lrun[rgi] = 0.f; }

    // ---- lower-phase prologue: window cols 0..63 (j = T-t0-64 ..) ----
    stage_r(T - t0 - 64);
    __syncthreads();
    qr_half(a_qrl, 0);

    for (int s0 = 0; s0 < T; s0 += 64) {
        const bool lower = (s0 <= t0);
        const int n      = lower ? (s0 >> 6) : ((s0 - t0) >> 6);
        const int rbase  = (n & 1) * 64;
        const int wbase  = 64 - rbase;
        const int wstart = lower ? (s0 + T - t0 - 64) : (s0 - t0 - 65);

        __syncthreads();   // B_top: prev tile's reads of r/k/v/p/qp done

        // ---- stage K, V, new 64 r rows ----
        #pragma unroll
        for (int idx = tid; idx < 512; idx += 256) {
            const int row = idx >> 3, c = (idx & 7) * 8;
            st8(&k_ls[row * 68 + c], *(const ushort8*)(kg + (size_t)(s0 + row) * DHEAD + c));
            st8(&v_ls[row * 68 + c], *(const ushort8*)(vtg + (size_t)row * T + s0 + c));
        }
        stage_r(wstart + 64);
        __syncthreads();   // B0

        // ---- AC ----
        floatx4 acf[4];
        #pragma unroll
        for (int ct = 0; ct < 4; ++ct) {
            acf[ct] = (floatx4){0.f, 0.f, 0.f, 0.f};
            #pragma unroll
            for (int ks = 0; ks < 2; ++ks) {
                short8 bfr = ld_frag(&k_ls[(16 * ct + m16) * 68 + ks * 32 + quad * 8]);
                acf[ct] = MFMA16(a_ac[ks], bfr, acf[ct]);
            }
        }
        // ---- QR: new 64 window cols -> ring ----
        qr_half(lower ? a_qrl : a_qru, wbase);
        __syncthreads();   // B1

        // ---- assemble from ring ----
        #pragma unroll
        for (int ct = 0; ct < 4; ++ct) {
            #pragma unroll
            for (int rgi = 0; rgi < 4; ++rgi) {
                const int i = 16 * w + quad * 4 + rgi;
                const int u = 16 * ct + m16;
                const int slot = ((63 - i + u) + rbase) & 127;
                const float v = b2f(qp_s[i * 133 + slot]);
                bool take;
                if (s0 < t0)       take = true;                 // all s < t
                else if (s0 == t0) take = (u <= i);             // s <= t
                else               take = (u != i + 1 + t0 - s0 + 64) || (s0 + u != t0 + i + 1);
                if (s0 > t0) take = (s0 + u != t0 + i + 1);
                if (take) acf[ct][rgi] += v;
            }
        }

        // ---- transition tile: upper full-window prologue + upper assemble ----
        if (s0 == t0) {
            __syncthreads();                 // lower assemble reads of qp done
            stage_r(-65);
            __syncthreads();
            qr_half(a_qru, 0);
            __syncthreads();
            stage_r(-1);
            __syncthreads();
            qr_half(a_qru, 64);
            __syncthreads();
            #pragma unroll
            for (int ct = 0; ct < 4; ++ct) {
                #pragma unroll
                for (int rgi = 0; rgi < 4; ++rgi) {
                    const int i = 16 * w + quad * 4 + rgi;
                    const int u = 16 * ct + m16;
                    if (u >= i + 2)
                        acf[ct][rgi] += b2f(qp_s[i * 133 + 63 - i + u]);
                }
            }
        }

        // ---- online softmax ----
        float alpha[4];
        #pragma unroll
        for (int rgi = 0; rgi < 4; ++rgi) {
            float mx = fmaxf(fmaxf(acf[0][rgi], acf[1][rgi]),
                             fmaxf(acf[2][rgi], acf[3][rgi]));
            #pragma unroll
            for (int off = 1; off < 16; off <<= 1)
                mx = fmaxf(mx, __shfl_xor(mx, off));
            const float mn = fmaxf(mrun[rgi], mx);
            alpha[rgi] = __expf(mrun[rgi] - mn);
            mrun[rgi] = mn;
            float s4 = 0.f;
            #pragma unroll
            for (int ct = 0; ct < 4; ++ct) {
                const float p = __expf(acf[ct][rgi] - mn);
                acf[ct][rgi] = p;
                s4 += p;
            }
            #pragma unroll
            for (int off = 1; off < 16; off <<= 1)
                s4 += __shfl_xor(s4, off);
            lrun[rgi] = lrun[rgi] * alpha[rgi] + s4;
        }
        #pragma unroll
        for (int ct = 0; ct < 4; ++ct)
            #pragma unroll
            for (int rgi = 0; rgi < 4; ++rgi) O[ct][rgi] *= alpha[rgi];

        // ---- write P ----
        #pragma unroll
        for (int ct = 0; ct < 4; ++ct)
            #pragma unroll
            for (int rgi = 0; rgi < 4; ++rgi)
                p_s[(16 * w + quad * 4 + rgi) * 68 + 16 * ct + m16] = f2b(acf[ct][rgi]);
        __syncthreads();   // B2

        // ---- PV ----
        short8 ap[2];
        {
            const unsigned short* p = &p_s[(16 * w + m16) * 68 + quad * 8];
            ap[0] = ld_frag(p); ap[1] = ld_frag(p + 32);
        }
        #pragma unroll
        for (int ct = 0; ct < 4; ++ct) {
            #pragma unroll
            for (int ks = 0; ks < 2; ++ks) {
                short8 bfr = ld_frag(&v_ls[(16 * ct + m16) * 68 + ks * 32 + quad * 8]);
                O[ct] = MFMA16(ap[ks], bfr, O[ct]);
            }
        }
    }

    // ---- write ctx bf16 [T,B,E] ----
    #pragma unroll
    for (int rgi = 0; rgi < 4; ++rgi) {
        const int t = t0 + 16 * w + quad * 4 + rgi;
        const float inv = 1.f / lrun[rgi];
        #pragma unroll
        for (int ct = 0; ct < 4; ++ct)
            ctx[((size_t)t * BATCH + b) * EMB + h * DHEAD + 16 * ct + m16] = f2b(O[ct][rgi] * inv);
    }
}

// ---------------------------------------------------------------------------
// Workspace (ushort offsets): q_s 0 | k_s 2097152 | v_s 4194304 | vT 6291456 |
// r_b 8388608 | ctx_b 9437184 | end 11534336 (= 23 MB)
// ---------------------------------------------------------------------------
extern "C" void kernel_launch(void* const* d_in, const int* in_sizes, int n_in,
                              void* d_out, int out_size, void* d_ws, size_t ws_size,
                              hipStream_t stream)
{
    const float* input = (const float*)d_in[0];
    const float* pos   = (const float*)d_in[1];
    const float* w_in  = (const float*)d_in[2];
    const float* w_out = (const float*)d_in[3];
    const float* w_pos = (const float*)d_in[4];
    const float* b_in  = (const float*)d_in[5];
    const float* b_out = (const float*)d_in[6];
    const float* b_pos = (const float*)d_in[7];
    const float* rwb   = (const float*)d_in[8];
    const float* rrb   = (const float*)d_in[9];

    unsigned short* ws    = (unsigned short*)d_ws;
    unsigned short* q_s   = ws;
    unsigned short* k_s   = ws + 2097152;
    unsigned short* v_s   = ws + 4194304;
    unsigned short* vT    = ws + 6291456;
    unsigned short* r_b   = ws + 8388608;
    unsigned short* ctx_b = ws + 9437184;

    gemm_bf16<0><<<dim3(12, 32), 256, 0, stream>>>(input, w_in, b_in, q_s, k_s, v_s, EMB);
    gemm_bf16<1><<<dim3(4, 16), 256, 0, stream>>>(pos, w_pos, b_pos, r_b, nullptr, nullptr, EMB);
    transpose_v<<<dim3(32, 16), 256, 0, stream>>>(v_s, vT);
    attn_mfma<<<dim3(32, 16), 256, 0, stream>>>(q_s, k_s, vT, r_b, rwb, rrb, ctx_b);
    gemm_bf16<2><<<dim3(4, 32), 256, 0, stream>>>(ctx_b, w_out, b_out, d_out, nullptr, nullptr, EMB);
}

// Round 5
// 273.478 us; speedup vs baseline: 7.8797x; 1.0675x over previous
//
#include <hip/hip_runtime.h>

#define T_SEQ 2048
#define BATCH 2
#define HEADS 8
#define DHEAD 64
#define EMB   512
#define NSPLIT 2

typedef __attribute__((ext_vector_type(8))) short short8;
typedef __attribute__((ext_vector_type(4))) short short4v;
typedef __attribute__((ext_vector_type(4))) float floatx4;
typedef __attribute__((ext_vector_type(8))) unsigned short ushort8;
typedef __attribute__((ext_vector_type(4))) unsigned short ushort4v;

__device__ __forceinline__ unsigned short f2b(float f) {
    union { float f; unsigned u; } v; v.f = f;
    unsigned r = v.u + 0x7fffu + ((v.u >> 16) & 1u);   // RNE to bf16
    return (unsigned short)(r >> 16);
}
__device__ __forceinline__ float b2f(unsigned short s) {
    union { unsigned u; float f; } v; v.u = ((unsigned)s) << 16; return v.f;
}
__device__ __forceinline__ short8 ld_frag(const unsigned short* p) {
    short4v lo = *(const short4v*)p;
    short4v hi = *(const short4v*)(p + 4);
    short8 r;
    r[0] = lo[0]; r[1] = lo[1]; r[2] = lo[2]; r[3] = lo[3];
    r[4] = hi[0]; r[5] = hi[1]; r[6] = hi[2]; r[7] = hi[3];
    return r;
}
__device__ __forceinline__ void st8(unsigned short* p, ushort8 v) {
    ushort4v lo = { v[0], v[1], v[2], v[3] };
    ushort4v hi = { v[4], v[5], v[6], v[7] };
    *(ushort4v*)p = lo;
    *(ushort4v*)(p + 4) = hi;
}
#define MFMA16(a, b, c) __builtin_amdgcn_mfma_f32_16x16x32_bf16(a, b, c, 0, 0, 0)

// ---------------------------------------------------------------------------
// One-shot fp32 -> bf16 conversion of all 5 tensors (compile-time segments).
// Segment boundaries in float4 units:
//   input 524288 | pos 262144 | w_in 196608 | w_pos 65536 | w_out 65536
// ---------------------------------------------------------------------------
__global__ __launch_bounds__(256)
void cvt_all(const float* __restrict__ s0, const float* __restrict__ s1,
             const float* __restrict__ s2, const float* __restrict__ s3,
             const float* __restrict__ s4,
             unsigned short* __restrict__ d0, unsigned short* __restrict__ d1,
             unsigned short* __restrict__ d2, unsigned short* __restrict__ d3,
             unsigned short* __restrict__ d4)
{
    const int i = blockIdx.x * 256 + threadIdx.x;
    const float* s; unsigned short* d; int off;
    if      (i <  524288) { s = s0; d = d0; off = i; }
    else if (i <  786432) { s = s1; d = d1; off = i -  524288; }
    else if (i <  983040) { s = s2; d = d2; off = i -  786432; }
    else if (i < 1048576) { s = s3; d = d3; off = i -  983040; }
    else if (i < 1114112) { s = s4; d = d4; off = i - 1048576; }
    else return;
    const float4 v = ((const float4*)s)[off];
    ushort4v o = { f2b(v.x), f2b(v.y), f2b(v.z), f2b(v.w) };
    ((ushort4v*)d)[off] = o;
}

// ---------------------------------------------------------------------------
// bf16 MFMA GEMM (pure bf16 staging): C[m,n] = sum_k A[m,k]*B[n,k] + bias[n]
// 128x128 tile, 4 waves 2x2, BK=32.
// MODE 0: QKV -> q_s/k_s/v_s bf16 [B,H,T,D];  MODE 1: r bf16 [R,E];
// MODE 2: fp32 out [m*EMB+n]
// ---------------------------------------------------------------------------
template<int MODE>
__global__ __launch_bounds__(256)
void gemm_bf16(const unsigned short* __restrict__ A, const unsigned short* __restrict__ B,
               const float* __restrict__ bias, void* __restrict__ out0,
               void* __restrict__ out1, void* __restrict__ out2, int K)
{
    __shared__ unsigned short As[128 * 36];
    __shared__ unsigned short Bs[128 * 36];
    const int bm  = blockIdx.y * 128;
    const int bn  = blockIdx.x * 128;
    const int tid = threadIdx.x;
    const int lane = tid & 63, w = tid >> 6;
    const int m16 = lane & 15, quad = lane >> 4;
    const int wm = (w & 1) * 64, wn = (w >> 1) * 64;

    floatx4 acc[4][4];
    #pragma unroll
    for (int i = 0; i < 4; ++i)
        #pragma unroll
        for (int j = 0; j < 4; ++j) acc[i][j] = (floatx4){0.f, 0.f, 0.f, 0.f};

    for (int k0 = 0; k0 < K; k0 += 32) {
        #pragma unroll
        for (int s = tid; s < 512; s += 256) {
            const int row = s >> 2, c = (s & 3) * 8;
            st8(&As[row * 36 + c], *(const ushort8*)(A + (size_t)(bm + row) * K + k0 + c));
            st8(&Bs[row * 36 + c], *(const ushort8*)(B + (size_t)(bn + row) * K + k0 + c));
        }
        __syncthreads();
        short8 af[4], bf[4];
        #pragma unroll
        for (int f = 0; f < 4; ++f) {
            af[f] = ld_frag(&As[(wm + f * 16 + m16) * 36 + quad * 8]);
            bf[f] = ld_frag(&Bs[(wn + f * 16 + m16) * 36 + quad * 8]);
        }
        #pragma unroll
        for (int fm = 0; fm < 4; ++fm)
            #pragma unroll
            for (int fn = 0; fn < 4; ++fn)
                acc[fm][fn] = MFMA16(af[fm], bf[fn], acc[fm][fn]);
        __syncthreads();
    }

    #pragma unroll
    for (int fn = 0; fn < 4; ++fn) {
        const int n = bn + wn + fn * 16 + m16;
        const float bv = bias[n];
        #pragma unroll
        for (int fm = 0; fm < 4; ++fm) {
            #pragma unroll
            for (int rgi = 0; rgi < 4; ++rgi) {
                const int m = bm + wm + fm * 16 + quad * 4 + rgi;
                const float val = acc[fm][fn][rgi] + bv;
                if (MODE == 0) {
                    const int t = m >> 1, b = m & 1;
                    const int reg = n >> 9, c = n & 511, h = c >> 6, dd = c & 63;
                    unsigned short* dst = (unsigned short*)(reg == 0 ? out0 : (reg == 1 ? out1 : out2));
                    dst[((size_t)(b * HEADS + h) * T_SEQ + t) * DHEAD + dd] = f2b(val);
                } else if (MODE == 1) {
                    ((unsigned short*)out0)[(size_t)m * EMB + n] = f2b(val);
                } else {
                    ((float*)out0)[(size_t)m * EMB + n] = val;
                }
            }
        }
    }
}

// ---------------------------------------------------------------------------
// bf16 transpose: v_s [B,H,T,D] -> vT [B,H,D,T]
// ---------------------------------------------------------------------------
__global__ __launch_bounds__(256)
void transpose_v(const unsigned short* __restrict__ v_s, unsigned short* __restrict__ vT)
{
    __shared__ unsigned short tile[64 * 68];
    const int t0 = blockIdx.x * 64, bh = blockIdx.y;
    const int tid = threadIdx.x;
    const unsigned short* src = v_s + ((size_t)bh * T_SEQ + t0) * DHEAD;
    #pragma unroll
    for (int s = tid; s < 512; s += 256) {
        const int row = s >> 3, c = (s & 7) * 8;
        st8(&tile[row * 68 + c], *(const ushort8*)(src + row * DHEAD + c));
    }
    __syncthreads();
    unsigned short* dst = vT + (size_t)bh * DHEAD * T_SEQ + t0;
    #pragma unroll
    for (int s = tid; s < 512; s += 256) {
        const int d = s >> 3, c = (s & 7) * 8;
        ushort8 o;
        #pragma unroll
        for (int j = 0; j < 8; ++j) o[j] = tile[(c + j) * 68 + d];
        *(ushort8*)(dst + (size_t)d * T_SEQ + c) = o;
    }
}

// ---------------------------------------------------------------------------
// Split-s fused MFMA attention with rolling-QR ring. blockIdx.z = s-split.
// Each block: 64 q rows, s-range [sp*T/NSPLIT, (sp+1)*T/NSPLIT), partial
// (O, m, l) out (O bf16 unnormalized, m/l fp32).
//   bd[t][s] = QR[t][T-1-t+s] (s<=t) | 0 (s==t+1) | QR[t+1][s-t-2] (s>=t+2)
// ---------------------------------------------------------------------------
__global__ __launch_bounds__(256)
void attn_mfma(const unsigned short* __restrict__ qg_, const unsigned short* __restrict__ kg_,
               const unsigned short* __restrict__ vtg_, const unsigned short* __restrict__ rg_,
               const float* __restrict__ rwb, const float* __restrict__ rrb,
               unsigned short* __restrict__ pO, float* __restrict__ pml)
{
    const int T   = T_SEQ;
    const int tb  = blockIdx.x;
    const int t0  = tb * 64;
    const int bh  = blockIdx.y;
    const int sp  = blockIdx.z;
    const int ss  = sp * (T / NSPLIT);
    const int se  = ss + (T / NSPLIT);
    const int h   = bh & 7;
    const int tid = threadIdx.x;
    const int lane = tid & 63;
    const int w    = tid >> 6;
    const int m16  = lane & 15;
    const int quad = lane >> 4;

    __shared__ unsigned short lds[25992];
    unsigned short* qrw_s = lds;            // 64 x 68 (pre-loop)
    unsigned short* qrr_s = lds + 4352;     // 65 x 68 (pre-loop)
    unsigned short* r_s   = lds;            // 64 x 68 (in-loop, aliases qrw)
    unsigned short* k_ls  = lds + 4352;     // 64 x 68 (in-loop, aliases qrr)
    unsigned short* v_ls  = lds + 8776;     // 64 x 68
    unsigned short* p_s   = lds + 13128;    // 64 x 68
    unsigned short* qp_s  = lds + 17480;    // 64 x 133 ring (cols 0..127)

    const unsigned short* qg  = qg_  + ((size_t)bh * T + t0) * DHEAD;
    const unsigned short* kg  = kg_  + (size_t)bh * T * DHEAD;
    const unsigned short* vtg = vtg_ + (size_t)bh * DHEAD * T;
    const unsigned short* rg  = rg_  + h * DHEAD;

    // ---- stage q tiles: (q + bias) * 0.125, bf16 ----
    for (int idx = tid; idx < 65 * 16; idx += 256) {
        const int row = idx >> 4, c = (idx & 15) << 2;
        ushort4v qv = {0, 0, 0, 0};
        if (t0 + row < T) qv = *(const ushort4v*)(qg + row * DHEAD + c);
        const float4 rr = *(const float4*)(rrb + h * DHEAD + c);
        qrr_s[row * 68 + c + 0] = f2b((b2f(qv[0]) + rr.x) * 0.125f);
        qrr_s[row * 68 + c + 1] = f2b((b2f(qv[1]) + rr.y) * 0.125f);
        qrr_s[row * 68 + c + 2] = f2b((b2f(qv[2]) + rr.z) * 0.125f);
        qrr_s[row * 68 + c + 3] = f2b((b2f(qv[3]) + rr.w) * 0.125f);
        if (row < 64) {
            const float4 rw = *(const float4*)(rwb + h * DHEAD + c);
            qrw_s[row * 68 + c + 0] = f2b((b2f(qv[0]) + rw.x) * 0.125f);
            qrw_s[row * 68 + c + 1] = f2b((b2f(qv[1]) + rw.y) * 0.125f);
            qrw_s[row * 68 + c + 2] = f2b((b2f(qv[2]) + rw.z) * 0.125f);
            qrw_s[row * 68 + c + 3] = f2b((b2f(qv[3]) + rw.w) * 0.125f);
        }
    }
    __syncthreads();

    short8 a_ac[2], a_qrl[2], a_qru[2];
    {
        const unsigned short* p0 = &qrw_s[(16 * w + m16) * 68 + quad * 8];
        a_ac[0]  = ld_frag(p0);  a_ac[1]  = ld_frag(p0 + 32);
        const unsigned short* p1 = &qrr_s[(16 * w + m16) * 68 + quad * 8];
        a_qrl[0] = ld_frag(p1);  a_qrl[1] = ld_frag(p1 + 32);
        const unsigned short* p2 = &qrr_s[(16 * w + 1 + m16) * 68 + quad * 8];
        a_qru[0] = ld_frag(p2);  a_qru[1] = ld_frag(p2 + 32);
    }
    __syncthreads();   // q regions now reusable as r_s/k_ls

    auto stage_r = [&](int jbase) {
        for (int idx = tid; idx < 512; idx += 256) {
            const int row = idx >> 3, c = (idx & 7) * 8;
            int j = jbase + row; j = j < 0 ? 0 : (j > T - 1 ? T - 1 : j);
            st8(&r_s[row * 68 + c], *(const ushort8*)(rg + (size_t)j * EMB + c));
        }
    };
    auto qr_half = [&](const short8* aq, int slotbase) {
        #pragma unroll
        for (int cc = 0; cc < 4; ++cc) {
            floatx4 q4 = (floatx4){0.f, 0.f, 0.f, 0.f};
            #pragma unroll
            for (int ks = 0; ks < 2; ++ks) {
                short8 bfr = ld_frag(&r_s[(16 * cc + m16) * 68 + ks * 32 + quad * 8]);
                q4 = MFMA16(aq[ks], bfr, q4);
            }
            #pragma unroll
            for (int rgi = 0; rgi < 4; ++rgi)
                qp_s[(16 * w + quad * 4 + rgi) * 133 + slotbase + 16 * cc + m16] = f2b(q4[rgi]);
        }
    };

    floatx4 O[4];
    float mrun[4], lrun[4];
    #pragma unroll
    for (int ct = 0; ct < 4; ++ct) O[ct] = (floatx4){0.f, 0.f, 0.f, 0.f};
    #pragma unroll
    for (int rgi = 0; rgi < 4; ++rgi) { mrun[rgi] = -3.4e38f; lrun[rgi] = 0.f; }

    // ---- prologue: fill the "old" 64 window cols for the first tile ----
    {
        const bool startLower = (ss <= t0);
        const int wstart0 = startLower ? (ss + T - t0 - 64) : (ss - t0 - 65);
        const int n0      = startLower ? (ss >> 6) : ((ss - t0) >> 6);
        stage_r(wstart0);
        __syncthreads();
        qr_half(startLower ? a_qrl : a_qru, (n0 & 1) * 64);
    }

    for (int s0 = ss; s0 < se; s0 += 64) {
        const bool lower = (s0 <= t0);
        const int n      = lower ? (s0 >> 6) : ((s0 - t0) >> 6);
        const int rbase  = (n & 1) * 64;
        const int wbase  = 64 - rbase;
        const int wstart = lower ? (s0 + T - t0 - 64) : (s0 - t0 - 65);

        __syncthreads();   // prior reads of r/k/v/p/qp done

        // ---- stage K, V, new 64 r rows ----
        #pragma unroll
        for (int idx = tid; idx < 512; idx += 256) {
            const int row = idx >> 3, c = (idx & 7) * 8;
            st8(&k_ls[row * 68 + c], *(const ushort8*)(kg + (size_t)(s0 + row) * DHEAD + c));
            st8(&v_ls[row * 68 + c], *(const ushort8*)(vtg + (size_t)row * T + s0 + c));
        }
        stage_r(wstart + 64);
        __syncthreads();   // B0

        // ---- AC ----
        floatx4 acf[4];
        #pragma unroll
        for (int ct = 0; ct < 4; ++ct) {
            acf[ct] = (floatx4){0.f, 0.f, 0.f, 0.f};
            #pragma unroll
            for (int ks = 0; ks < 2; ++ks) {
                short8 bfr = ld_frag(&k_ls[(16 * ct + m16) * 68 + ks * 32 + quad * 8]);
                acf[ct] = MFMA16(a_ac[ks], bfr, acf[ct]);
            }
        }
        // ---- QR: new 64 window cols -> ring ----
        qr_half(lower ? a_qrl : a_qru, wbase);
        __syncthreads();   // B1

        // ---- assemble from ring ----
        #pragma unroll
        for (int ct = 0; ct < 4; ++ct) {
            #pragma unroll
            for (int rgi = 0; rgi < 4; ++rgi) {
                const int i = 16 * w + quad * 4 + rgi;
                const int u = 16 * ct + m16;
                const int slot = ((63 - i + u) + rbase) & 127;
                const float v = b2f(qp_s[i * 133 + slot]);
                const bool take = (s0 < t0) ? true
                                : (s0 == t0) ? (u <= i)
                                : (s0 + u != t0 + i + 1);
                if (take) acf[ct][rgi] += v;
            }
        }

        // ---- transition tile: upper prologue + upper assemble ----
        if (s0 == t0) {
            __syncthreads();                 // qp/r reads done
            stage_r(-1);                     // j = -1..62 (clamped)
            __syncthreads();
            qr_half(a_qru, 64);              // slots 64..127: j = s-t-2
            __syncthreads();
            #pragma unroll
            for (int ct = 0; ct < 4; ++ct) {
                #pragma unroll
                for (int rgi = 0; rgi < 4; ++rgi) {
                    const int i = 16 * w + quad * 4 + rgi;
                    const int u = 16 * ct + m16;
                    if (u >= i + 2)
                        acf[ct][rgi] += b2f(qp_s[i * 133 + 63 - i + u]);
                }
            }
        }

        // ---- online softmax ----
        float alpha[4];
        #pragma unroll
        for (int rgi = 0; rgi < 4; ++rgi) {
            float mx = fmaxf(fmaxf(acf[0][rgi], acf[1][rgi]),
                             fmaxf(acf[2][rgi], acf[3][rgi]));
            #pragma unroll
            for (int off = 1; off < 16; off <<= 1)
                mx = fmaxf(mx, __shfl_xor(mx, off));
            const float mn = fmaxf(mrun[rgi], mx);
            alpha[rgi] = __expf(mrun[rgi] - mn);
            mrun[rgi] = mn;
            float s4 = 0.f;
            #pragma unroll
            for (int ct = 0; ct < 4; ++ct) {
                const float p = __expf(acf[ct][rgi] - mn);
                acf[ct][rgi] = p;
                s4 += p;
            }
            #pragma unroll
            for (int off = 1; off < 16; off <<= 1)
                s4 += __shfl_xor(s4, off);
            lrun[rgi] = lrun[rgi] * alpha[rgi] + s4;
        }
        #pragma unroll
        for (int ct = 0; ct < 4; ++ct)
            #pragma unroll
            for (int rgi = 0; rgi < 4; ++rgi) O[ct][rgi] *= alpha[rgi];

        // ---- write P ----
        #pragma unroll
        for (int ct = 0; ct < 4; ++ct)
            #pragma unroll
            for (int rgi = 0; rgi < 4; ++rgi)
                p_s[(16 * w + quad * 4 + rgi) * 68 + 16 * ct + m16] = f2b(acf[ct][rgi]);
        __syncthreads();   // B2

        // ---- PV ----
        short8 ap[2];
        {
            const unsigned short* p = &p_s[(16 * w + m16) * 68 + quad * 8];
            ap[0] = ld_frag(p); ap[1] = ld_frag(p + 32);
        }
        #pragma unroll
        for (int ct = 0; ct < 4; ++ct) {
            #pragma unroll
            for (int ks = 0; ks < 2; ++ks) {
                short8 bfr = ld_frag(&v_ls[(16 * ct + m16) * 68 + ks * 32 + quad * 8]);
                O[ct] = MFMA16(ap[ks], bfr, O[ct]);
            }
        }
    }

    // ---- write partial O (bf16, unnormalized) + (m, l) ----
    unsigned short* po = pO + (((size_t)sp * 16 + bh) * 32 + tb) * 4096;
    float* ml          = pml + (((size_t)sp * 16 + bh) * 32 + tb) * 128;
    #pragma unroll
    for (int rgi = 0; rgi < 4; ++rgi) {
        const int i = 16 * w + quad * 4 + rgi;
        #pragma unroll
        for (int ct = 0; ct < 4; ++ct)
            po[i * 64 + 16 * ct + m16] = f2b(O[ct][rgi]);
        if (m16 == 0) { ml[i * 2] = mrun[rgi]; ml[i * 2 + 1] = lrun[rgi]; }
    }
}

// ---------------------------------------------------------------------------
// Merge NSPLIT partials -> ctx bf16 [T,B,E]
// ---------------------------------------------------------------------------
__global__ __launch_bounds__(256)
void merge_attn(const unsigned short* __restrict__ pO, const float* __restrict__ pml,
                unsigned short* __restrict__ ctx)
{
    const int tb = blockIdx.x, bh = blockIdx.y;
    const int h = bh & 7, b = bh >> 3;
    const int tid = threadIdx.x;
    const int row = tid >> 2, cseg = (tid & 3) * 16;

    const size_t blk0 = (((size_t)0 * 16 + bh) * 32 + tb);
    const size_t blk1 = (((size_t)1 * 16 + bh) * 32 + tb);
    const float m0 = pml[blk0 * 128 + row * 2],     l0 = pml[blk0 * 128 + row * 2 + 1];
    const float m1 = pml[blk1 * 128 + row * 2],     l1 = pml[blk1 * 128 + row * 2 + 1];
    const float mn = fmaxf(m0, m1);
    const float w0 = __expf(m0 - mn), w1 = __expf(m1 - mn);
    const float inv = 1.f / (l0 * w0 + l1 * w1);

    const unsigned short* o0 = pO + blk0 * 4096 + row * 64 + cseg;
    const unsigned short* o1 = pO + blk1 * 4096 + row * 64 + cseg;
    unsigned short* dst = ctx + ((size_t)(tb * 64 + row) * BATCH + b) * EMB + h * 64 + cseg;
    #pragma unroll
    for (int j = 0; j < 16; ++j)
        dst[j] = f2b((b2f(o0[j]) * w0 + b2f(o1[j]) * w1) * inv);
}

// ---------------------------------------------------------------------------
// Workspace (ushort offsets), total 15,990,784 ush = 31.98 MB (proven size):
//   0        inb     2,097,152   \
//   2097152  posb    1,048,576    | dead after the GEMMs/transpose ->
//   3145728  w_inb     786,432    | overlaid by partials:
//   3932160  w_posb    262,144    |   pO  bf16 @0        (4,194,304 ush)
//   4194304  v_s     2,097,152   /    pml fp32 @4194304  (262,144 ush)
//   6291456  w_outb    262,144
//   6553600  q_s     2,097,152
//   8650752  k_s     2,097,152
//   10747904 vT      2,097,152
//   12845056 r_b     1,048,576
//   13893632 ctx_b   2,097,152
// ---------------------------------------------------------------------------
extern "C" void kernel_launch(void* const* d_in, const int* in_sizes, int n_in,
                              void* d_out, int out_size, void* d_ws, size_t ws_size,
                              hipStream_t stream)
{
    const float* input = (const float*)d_in[0];
    const float* pos   = (const float*)d_in[1];
    const float* w_in  = (const float*)d_in[2];
    const float* w_out = (const float*)d_in[3];
    const float* w_pos = (const float*)d_in[4];
    const float* b_in  = (const float*)d_in[5];
    const float* b_out = (const float*)d_in[6];
    const float* b_pos = (const float*)d_in[7];
    const float* rwb   = (const float*)d_in[8];
    const float* rrb   = (const float*)d_in[9];

    unsigned short* ws     = (unsigned short*)d_ws;
    unsigned short* inb    = ws;
    unsigned short* posb   = ws + 2097152;
    unsigned short* w_inb  = ws + 3145728;
    unsigned short* w_posb = ws + 3932160;
    unsigned short* v_s    = ws + 4194304;
    unsigned short* w_outb = ws + 6291456;
    unsigned short* q_s    = ws + 6553600;
    unsigned short* k_s    = ws + 8650752;
    unsigned short* vT     = ws + 10747904;
    unsigned short* r_b    = ws + 12845056;
    unsigned short* ctx_b  = ws + 13893632;
    unsigned short* pO     = ws;                       // overlay
    float*          pml    = (float*)(ws + 4194304);   // overlay

    cvt_all<<<4352, 256, 0, stream>>>(input, pos, w_in, w_pos, w_out,
                                      inb, posb, w_inb, w_posb, w_outb);
    gemm_bf16<0><<<dim3(12, 32), 256, 0, stream>>>(inb, w_inb, b_in, q_s, k_s, v_s, EMB);
    gemm_bf16<1><<<dim3(4, 16), 256, 0, stream>>>(posb, w_posb, b_pos, r_b, nullptr, nullptr, EMB);
    transpose_v<<<dim3(32, 16), 256, 0, stream>>>(v_s, vT);
    attn_mfma<<<dim3(32, 16, NSPLIT), 256, 0, stream>>>(q_s, k_s, vT, r_b, rwb, rrb, pO, pml);
    merge_attn<<<dim3(32, 16), 256, 0, stream>>>(pO, pml, ctx_b);
    gemm_bf16<2><<<dim3(4, 32), 256, 0, stream>>>(ctx_b, w_outb, b_out, d_out, nullptr, nullptr, EMB);
}